// Round 1
// 75.770 us; speedup vs baseline: 1.0281x; 1.0281x over previous
//
#include <hip/hip_runtime.h>
#include <cmath>
#include <cstdint>

// Problem: B=2, C=32, Z=4, E=2, N=4096. One candidate point per lattice cell,
// cell pitch (0.78125, 0.78125, 0.75); offsets in [0,1) cell units.
// => dist < ele_d (0.74 / 0.528) pairs confined to 3x3x3 cells.
// => any point outside the xy +-2 window is >= 1.5625*(1-eps) away: a
//    neighborhood argmin < GUARD=1.4999 is provably the global argmin.
//
// Structure (2 kernels, was 4): the 77.9us baseline was epoch-bound (4 serial
// launches over L2-resident ~0.5MB inputs). K1+K2 fuse via LDS halo restrain
// (3x recompute redundancy, trivially cheap); K3+K4 fuse via inline rare
// fallback (the quad that fails the guard does its own full 4096-pt scan).
namespace {
constexpr int NPT  = 4096;

// output offsets (floats), reference return order
constexpr int O_PPOS  = 0;
constexpr int O_MASKP = 49152;
constexpr int O_KEEP  = 65536;
constexpr int O_TPOS  = 81920;
constexpr int O_MASKT = 131072;
constexpr int O_TPT   = 147456;
constexpr int O_TPP   = 163840;
constexpr int O_TPTN  = 180224;
constexpr int O_TPPN  = 196608;

constexpr float GUARD = 1.4999f;
} // namespace

__device__ __forceinline__ unsigned long long shfl_xor_u64(unsigned long long v, int m) {
    unsigned lo = (unsigned)v, hi = (unsigned)(v >> 32);
    lo = __shfl_xor(lo, m); hi = __shfl_xor(hi, m);
    return ((unsigned long long)hi << 32) | lo;
}

// position from raw input + cell index — bit-identical everywhere (contract off,
// lattice constants 25/32 and 3/4 are exactly representable)
__device__ __forceinline__ float3 cellpos(float4 p, int n) {
#pragma clang fp contract(off)
    float fx = (float)(n >> 7), fy = (float)((n >> 2) & 31), fz = (float)(n & 3);
    float3 r;
    r.x = (p.x + fx) * 0.78125f;
    r.y = (p.y + fy) * 0.78125f;
    r.z = (p.z + fz) * 0.75f;
    return r;
}
__device__ __forceinline__ float dist2(float3 a, float3 b) {
#pragma clang fp contract(off)
    float dx = a.x - b.x, dy = a.y - b.y, dz = a.z - b.z;
    float d2 = dx * dx + dy * dy;
    return d2 + dz * dz;   // numpy sum order: (x+y)+z
}

// ---------------------------------------------------------------------------
// KA: fused restrain + suppress. One block per (s, gx, gy-half).
// Phase 1: restrain counts for the 3x18x4 halo region -> LDS.
// Phase 2: suppression for the 64 interior rows (4 threads/row), write
//          p_pos / mask_p / keep outputs + keepu workspace.
__global__ void __launch_bounds__(256) k_nms(const float4* __restrict__ pred,
                                             float* __restrict__ out,
                                             unsigned char* __restrict__ keepu,
                                             float s0, float s1) {
#pragma clang fp contract(off)
    __shared__ unsigned char restr[216];          // [rgx 3][rgy 18][z 4]
    int bid = blockIdx.x;
    int h2 = bid & 1, gx = (bid >> 1) & 31, s = bid >> 6;
    int b = s >> 1, e = s & 1;
    int base4 = b * 8192 + e;
    float se = (s & 1) ? s1 : s0;
    int gy0 = h2 << 4;
    int t = (int)threadIdx.x;

    // phase 1: one thread per halo point
    if (t < 216) {
        int rgx = t / 72, rem = t - rgx * 72, rgy = rem >> 2, z = rem & 3;
        int px = gx + rgx - 1, py = gy0 + rgy - 1;
        unsigned c = 0;
        if ((unsigned)px < 32u && (unsigned)py < 32u) {
            int pn = px * 128 + py * 4 + z;
            float4 p = pred[base4 + pn * 2];
            if (p.w > 0.5f) {
                float3 pj = cellpos(p, pn);
                for (int q = 0; q < 9; ++q) {
                    int nx = px + q / 3 - 1, ny = py + q % 3 - 1;
                    if ((unsigned)nx > 31u || (unsigned)ny > 31u) continue;
                    int nb = nx * 128 + ny * 4;
#pragma unroll
                    for (int nz = 0; nz < 4; ++nz) {
                        int ni = nb + nz;
                        float4 pi = pred[base4 + ni * 2];
                        float3 qi = cellpos(pi, ni);
                        float d2 = dist2(pj, qi);
                        bool prec = (pi.w > p.w) || ((pi.w == p.w) && (ni < pn));
                        if ((pi.w > 0.5f) && (d2 < se) && prec) c++;
                    }
                }
            }
        }
        restr[t] = (unsigned char)c;              // max 36, fits uchar
    }
    __syncthreads();

    // phase 2: 64 rows x 4 threads
    int r = t >> 2, h = t & 3;
    int gy = gy0 + (r >> 2), z = r & 3;
    int n = (gx << 7) + (gy << 2) + z;
    int row = s * NPT + n;
    float4 p = pred[base4 + n * 2];
    float3 pj = cellpos(p, n);
    bool valid = p.w > 0.5f;
    unsigned any = 0;
    if (valid) {
        for (int qq = 0; qq < 3; ++qq) {
            int q = qq * 4 + h;                   // h=0:{0,4,8} h=1:{1,5} h=2:{2,6} h=3:{3,7}
            if (q > 8) continue;
            int dx = q / 3 - 1, dy = q % 3 - 1;
            int nx = gx + dx, ny = gy + dy;
            if ((unsigned)nx > 31u || (unsigned)ny > 31u) continue;
            int nb = nx * 128 + ny * 4;
            const unsigned char* lr = &restr[(dx + 1) * 72 + (gy - gy0 + dy + 1) * 4];
#pragma unroll
            for (int nz = 0; nz < 4; ++nz) {
                int ni = nb + nz;
                float4 pi = pred[base4 + ni * 2];
                float3 qi = cellpos(pi, ni);
                float d2 = dist2(pj, qi);
                bool prec = (pi.w > p.w) || ((pi.w == p.w) && (ni < n));
                bool flg = (pi.w > 0.5f) && (lr[nz] == 0);
                if (flg && (d2 < se) && prec) any = 1u;
            }
        }
    }
    any |= __shfl_xor(any, 1);
    any |= __shfl_xor(any, 2);
    if (h == 0) {
        out[O_PPOS + row * 3 + 0] = pj.x;
        out[O_PPOS + row * 3 + 1] = pj.y;
        out[O_PPOS + row * 3 + 2] = pj.z;
        out[O_MASKP + row] = valid ? 1.0f : 0.0f;
        bool keep = valid && !any;
        out[O_KEEP + row] = keep ? 1.0f : 0.0f;
        keepu[row] = keep ? 1 : 0;
    }
}

// ---------------------------------------------------------------------------
// KB: fused match (both variants) with inline exact fallback.
// 4 threads/row: 5x5 xy window x full z; quad-combine; if the guard rejects
// either variant, the same quad does the exact full-row scan (rare).
__global__ void __launch_bounds__(256) k_match(const float4* __restrict__ pred,
                                               const float4* __restrict__ tgt,
                                               const unsigned char* __restrict__ keepu,
                                               float* __restrict__ out,
                                               float s0, float s1) {
#pragma clang fp contract(off)
    int tid = blockIdx.x * 256 + (int)threadIdx.x;
    int row = tid >> 2, h = tid & 3;
    int n = row & (NPT - 1), s = row >> 12, b = s >> 1, e = s & 1;
    int base4 = b * 8192 + e, srow = s * NPT;
    float se = (s & 1) ? s1 : s0;
    float4 t4 = tgt[base4 + n * 2];
    float3 tj = cellpos(t4, n);
    bool tv = t4.w > 0.5f;
    if (h == 0) {
        out[O_TPOS + row * 3 + 0] = tj.x;
        out[O_TPOS + row * 3 + 1] = tj.y;
        out[O_TPOS + row * 3 + 2] = tj.z;
        out[O_MASKT + row] = tv ? 1.0f : 0.0f;
    }
    if (!tv) {   // quad-uniform early out (all-inf row -> masks 0, idx 0)
        if (h == 0) {
            out[O_TPT + row] = 0.0f; out[O_TPTN + row] = 0.0f;
            out[O_TPP + row] = 0.0f; out[O_TPPN + row] = 0.0f;
        }
        return;
    }
    int gx = n >> 7, gy = (n >> 2) & 31;
    unsigned long long bs = ~0ull, bn = ~0ull;
    unsigned as_ = 0, an_ = 0;
    for (int qq = 0; qq < 7; ++qq) {
        int q = qq * 4 + h;                      // h=0 gets 7 cells, others 6
        if (q > 24) continue;
        int nx = gx + q / 5 - 2, ny = gy + q % 5 - 2;
        if ((unsigned)nx > 31u || (unsigned)ny > 31u) continue;
        int nb = nx * 128 + ny * 4;
#pragma unroll
        for (int nz = 0; nz < 4; ++nz) {
            int ni = nb + nz;
            float4 pi = pred[base4 + ni * 2];
            float3 qi = cellpos(pi, ni);
            float d2 = dist2(tj, qi);
            float dist = sqrtf(d2);
            unsigned long long enc =
                ((unsigned long long)__float_as_uint(dist) << 32) | (unsigned)ni;
            if (pi.w > 0.5f) { if (enc < bs) bs = enc; if (d2 < se) as_ = 1u; }
            if (keepu[srow + ni]) { if (enc < bn) bn = enc; if (d2 < se) an_ = 1u; }
        }
    }
    for (int m = 1; m < 4; m <<= 1) {            // combine across the row-quad
        unsigned long long o = shfl_xor_u64(bs, m); if (o < bs) bs = o;
        o = shfl_xor_u64(bn, m); if (o < bn) bn = o;
        as_ |= __shfl_xor(as_, m);
        an_ |= __shfl_xor(an_, m);
    }
    // empty best -> hi word 0xFFFFFFFF = NaN -> compare false -> fallback
    bool acc_s = __uint_as_float((unsigned)(bs >> 32)) < GUARD;
    bool acc_n = __uint_as_float((unsigned)(bn >> 32)) < GUARD;
    if (!(acc_s && acc_n)) {
        // exact full-row fallback by this quad (rare; bit-equal to window
        // result for the accepted variant by the GUARD proof)
        unsigned long long fs = ~0ull, fn = ~0ull;
        for (int k = h; k < NPT; k += 4) {
            float4 pi = pred[base4 + k * 2];
            float3 qi = cellpos(pi, k);
            float d2 = dist2(tj, qi);
            float dist = sqrtf(d2);
            unsigned long long enc =
                ((unsigned long long)__float_as_uint(dist) << 32) | (unsigned)k;
            if (pi.w > 0.5f && enc < fs) fs = enc;
            if (keepu[srow + k] && enc < fn) fn = enc;
        }
        for (int m = 1; m < 4; m <<= 1) {
            unsigned long long o = shfl_xor_u64(fs, m); if (o < fs) fs = o;
            o = shfl_xor_u64(fn, m); if (o < fn) fn = o;
        }
        bs = fs; bn = fn;
    }
    if (h == 0) {
        out[O_TPT + row]  = as_ ? 1.0f : 0.0f;
        out[O_TPTN + row] = an_ ? 1.0f : 0.0f;
        out[O_TPP + row]  = (float)((bs == ~0ull) ? 0u : (unsigned)(bs & 0xffffffffull));
        out[O_TPPN + row] = (float)((bn == ~0ull) ? 0u : (unsigned)(bn & 0xffffffffull));
    }
}

// ---------------------------------------------------------------------------
// host: smallest f with sqrtf(f) >= t, so (d2 < f) <=> (sqrtf(d2) < t) bit-exactly.
static float sq_boundary(float t) {
    float f = (float)((double)t * (double)t);
    while (sqrtf(f) >= t) f = nextafterf(f, 0.0f);
    while (sqrtf(f) < t)  f = nextafterf(f, __builtin_inff());
    return f;
}

extern "C" void kernel_launch(void* const* d_in, const int* in_sizes, int n_in,
                              void* d_out, int out_size, void* d_ws, size_t ws_size,
                              hipStream_t stream) {
    (void)in_sizes; (void)n_in; (void)out_size; (void)ws_size;
    const float4* pred = (const float4*)d_in[0];
    const float4* tgt  = (const float4*)d_in[1];
    float* out = (float*)d_out;
    unsigned char* keepu = (unsigned char*)d_ws;

    float s0 = sq_boundary(0.74f);    // ELE_D[0]
    float s1 = sq_boundary(0.528f);   // ELE_D[1]

    k_nms  <<<dim3(256), dim3(256), 0, stream>>>(pred, out, keepu, s0, s1);
    k_match<<<dim3(256), dim3(256), 0, stream>>>(pred, tgt, keepu, out, s0, s1);
}